// Round 15
// baseline (323.614 us; speedup 1.0000x reference)
//
#include <hip/hip_runtime.h>
#include <stdint.h>

// VanillaRNN fused: B=2048,S=125,I=2,H=300,O=2
// h_t = relu(x_t@W_ih^T + b_ih + h_{t-1}@W_hh^T + b_hh) + 0.01*noise_t
// out = h_t @ W_out^T + b_out
//
// R15: 4 waves x 80 cols at 1 WAVE/SIMD (the 512-reg regime).
//  - A-frag reads are K-driven (10/wave/step, irreducible) -> per-CU LDS
//    cost scales with WAVES. 10 waves spent ~1600cy/step on LDS; 4 waves
//    spend ~550cy, hidden under the (shape-invariant) 970cy MFMA work.
//  - wf = 5 tiles x 10 kt = 200 VGPR. At 1 wave/SIMD the budget is 512:
//    first config where W-residency is structurally guaranteed (R1-R9
//    all spilled at the 168/256-reg budgets).
//  - each ds_read_b128 h-frag feeds 5 MFMAs (1:5 read:MFMA).
//  - noise/x epilogue operands hoisted before MFMA (free regs now).
//  - noise DMA: 150 chunks/wave, 3 instrs/step uniform -> vmcnt(3)
//    counted barrier (2 slabs in flight across barriers).
//  - carried from R11/R13: swapped MFMA (A=W, B=h), x/bias as K-rows
//    300-302, W_out as cols 300/301 (wave 3, tile 3, grp 3), zero-row
//    Abuf, triple-buffered Nbuf, single-asm barrier, 6-period unroll.

#define SEQ   125
#define HID   300
#define APAD  328     // Abuf row stride in shorts
#define KT    10
#define NT    5       // 16-col tiles per wave (5*16 = 80 cols)
#define WAVES 4
#define NTH   (WAVES * 64)
#define RPW   8
#define NSLAB 2400    // floats per Nbuf slab

typedef __attribute__((ext_vector_type(8))) short bf16x8;
typedef __attribute__((ext_vector_type(4))) float f32x4;

__device__ __forceinline__ short f2bf(float f) {
  union { float f; uint32_t u; } v; v.f = f;
  uint32_t r = (v.u + 0x7fffu + ((v.u >> 16) & 1u)) >> 16;  // RNE
  return (short)r;
}

__device__ __forceinline__ uint32_t cvt_pk_bf16(float lo, float hi) {
  uint32_t r;
  asm("v_cvt_pk_bf16_f32 %0, %1, %2" : "=v"(r) : "v"(lo), "v"(hi));
  return r;
}

__device__ __forceinline__ void dma16(const float* g, float* l) {
  __builtin_amdgcn_global_load_lds(
      (const __attribute__((address_space(1))) unsigned int*)g,
      (__attribute__((address_space(3))) unsigned int*)l, 16, 0, 0);
}

// vmcnt(3): the 3 newest VMEM ops (this step's slab issue) may stay in
// flight; everything older (incl. next step's slab) has retired.
#define STEP_BARRIER() \
  asm volatile("s_waitcnt vmcnt(3) lgkmcnt(0)\n\ts_barrier" ::: "memory")

__global__ __launch_bounds__(NTH)
__attribute__((amdgpu_waves_per_eu(1, 1)))
void rnn_fused(
    const float* __restrict__ x,      // [2048,125,2]
    const float* __restrict__ noise,  // [2048,125,300]
    const float* __restrict__ W_ih,   // [300,2]
    const float* __restrict__ b_ih,   // [300]
    const float* __restrict__ W_hh,   // [300,300]
    const float* __restrict__ b_hh,   // [300]
    const float* __restrict__ W_out,  // [2,300]
    const float* __restrict__ b_out,  // [2]
    float* __restrict__ out)          // [2048,125,2]
{
  // rows 0..7 = batch rows' h (+x cols 300-301, bias col 302); row 8 = zeros
  __shared__ __align__(16) short Abuf[2][9][APAD];   // 11808 B
  __shared__ __align__(16) float Nbuf[3][NSLAB];     // 28800 B noise 3-buf
  __shared__ float xbuf[RPW][SEQ * 2];               //  8000 B
  __shared__ float outbuf[RPW][SEQ * 2];             //  8000 B

  const int tid  = threadIdx.x;
  const int wave = tid >> 6;
  const int lane = tid & 63;
  const int grp  = lane >> 4;     // 0..3
  const int lc   = lane & 15;     // 0..15
  const int row0 = blockIdx.x * RPW;
  const int grp8 = grp * 8;
  const int arow = (lc < 8) ? lc : 8;     // zero-row broadcast
  const bool lcr = (lc < 8);              // lane's batch row is real

  // zero both Abuf buffers (incl. zero-row + cols 303..327)
  for (int i = tid; i < 2 * 9 * APAD / 2; i += NTH)
    ((uint32_t*)Abuf)[i] = 0u;
  // stage x
  for (int i = tid; i < RPW * SEQ * 2; i += NTH) {
    int r = i / (SEQ * 2), j = i % (SEQ * 2);
    xbuf[r][j] = x[(row0 + r) * (SEQ * 2) + j];
  }

  const float bout0 = b_out[0], bout1 = b_out[1];

  // ---- persistent A-side fragments: wf[t][kt], lane holds W for col
  // c = wave*80 + t*16 + lc, k = kt*32 + grp*8 + e.
  // K-rows 300/301: W_ih cols; 302: b_ih+b_hh. Cols 300/301: W_out rows.
  bf16x8 wf[NT][KT];
#pragma unroll
  for (int t = 0; t < NT; ++t) {
    int c = wave * 80 + t * 16 + lc;
#pragma unroll
    for (int kt = 0; kt < KT; ++kt) {
      bf16x8 f;
#pragma unroll
      for (int e = 0; e < 8; ++e) {
        int k = kt * 32 + grp8 + e;
        float v = 0.f;
        if (c < HID) {
          if (k < HID)            v = W_hh[c * HID + k];
          else if (k == HID)      v = W_ih[c * 2 + 0];
          else if (k == HID + 1)  v = W_ih[c * 2 + 1];
          else if (k == HID + 2)  v = b_ih[c] + b_hh[c];
        } else if (c == HID) {
          if (k < HID)            v = W_out[k];
        } else if (c == HID + 1) {
          if (k < HID)            v = W_out[HID + k];
        }
        f[e] = f2bf(v);
      }
      wf[t][kt] = f;
    }
  }

  // ---- noise DMA: wave owns 150 chunks = 2 batch rows (2w, 2w+1).
  // round k covers r = 64k+lane (r<150); 3 instrs/step/wave uniform.
  const int r0 = lane;
  const int r1 = 64 + lane;
  const int r2 = (lane < 22) ? (128 + lane) : 149;   // clamped; exec-masked
  const float* g0 = noise + (size_t)(row0 + 2 * wave + r0 / 75) * (SEQ * HID) + (r0 % 75) * 4;
  const float* g1 = noise + (size_t)(row0 + 2 * wave + r1 / 75) * (SEQ * HID) + (r1 % 75) * 4;
  const float* g2 = noise + (size_t)(row0 + 2 * wave + r2 / 75) * (SEQ * HID) + (r2 % 75) * 4;
  float* const d0 = &Nbuf[0][wave * 600];

  __syncthreads();  // Abuf zeros + xbuf visible

  // post-zero init: x_0 into Abuf[0] cols 300-301; bias-one col 302 (both)
  if (tid < 8) {
    float2 xv = *(const float2*)&x[(size_t)(row0 + tid) * (SEQ * 2)];
    *(uint32_t*)&Abuf[0][tid][300] = cvt_pk_bf16(xv.x, xv.y);
    Abuf[0][tid][302] = (short)0x3F80;   // bf16 1.0
    Abuf[1][tid][302] = (short)0x3F80;
  }

  // prologue DMA: slabs 0 and 1 (6 instrs -> vmcnt(3) = slab 0 landed)
  dma16(g0, &Nbuf[0][wave * 600]);
  dma16(g1, &Nbuf[0][wave * 600 + 256]);
  if (lane < 22) dma16(g2, &Nbuf[0][wave * 600 + 512]);
  dma16(g0 + HID, &Nbuf[1][wave * 600]);
  dma16(g1 + HID, &Nbuf[1][wave * 600 + 256]);
  if (lane < 22) dma16(g2 + HID, &Nbuf[1][wave * 600 + 512]);
  int gofs = 2 * HID;
  STEP_BARRIER();

  const bool xw = (wave == 0) && (grp == 0) && lcr;  // lanes 0-7

  // Iteration S: MFMA on Abuf[CUR] (= h_{S-1} + x_S + bias); out[S-1]
  // from cols 300/301 (S>=1, wave3/t3/grp3); epilogue writes h_S + x_{S+1}.
#define STEPM(S, CUR, RB, WB, DO_OUT, DO_EPI, DO_X, DO_ADV, DO_DMA)            \
  {                                                                            \
    if (DO_DMA) {                                                              \
      dma16(g0 + gofs, &Nbuf[WB][wave * 600]);                                 \
      dma16(g1 + gofs, &Nbuf[WB][wave * 600 + 256]);                           \
      if (lane < 22) dma16(g2 + gofs, &Nbuf[WB][wave * 600 + 512]);            \
    }                                                                          \
    if (DO_ADV) gofs += HID;                                                   \
    /* hoisted epilogue operands (drain under MFMA; regs are plentiful) */     \
    float4 nzv[NT];                                                            \
    float2 xvh = {0.f, 0.f};                                                   \
    _Pragma("unroll")                                                          \
    for (int t = 0; t < NT; ++t) {                                             \
      nzv[t] = (float4){0.f, 0.f, 0.f, 0.f};                                   \
      int cbt = wave * 80 + t * 16 + grp * 4;                                  \
      if (DO_EPI && lcr && cbt < HID)                                          \
        nzv[t] = *(const float4*)&Nbuf[RB][lc * HID + cbt];                    \
    }                                                                          \
    if (DO_X) { if (xw) xvh = *(const float2*)&xbuf[lc][((S) + 1) * 2]; }      \
    /* MFMA: 10 h-frag reads, each feeds 5 tiles (50 MFMAs, 5 chains) */       \
    const short* Ab = &Abuf[CUR][arow][grp8];                                  \
    f32x4 ac[NT];                                                              \
    _Pragma("unroll")                                                          \
    for (int t = 0; t < NT; ++t) ac[t] = (f32x4){0.f, 0.f, 0.f, 0.f};          \
    _Pragma("unroll")                                                          \
    for (int kt = 0; kt < KT; ++kt) {                                          \
      bf16x8 hh = *(const bf16x8*)(Ab + kt * 32);                              \
      _Pragma("unroll")                                                        \
      for (int t = 0; t < NT; ++t)                                             \
        ac[t] = __builtin_amdgcn_mfma_f32_16x16x32_bf16(wf[t][kt], hh, ac[t], 0, 0, 0); \
    }                                                                          \
    if (DO_OUT) { if (wave == 3 && grp == 3 && lcr) {                          \
      float2 o; o.x = ac[3][0] + bout0; o.y = ac[3][1] + bout1;                \
      *(float2*)&outbuf[lc][((S) - 1) * 2] = o;                                \
    } }                                                                        \
    if (DO_EPI) { if (lcr) {                                                   \
      _Pragma("unroll")                                                        \
      for (int t = 0; t < NT; ++t) {                                           \
        int cbt = wave * 80 + t * 16 + grp * 4;                                \
        if (cbt < HID) {                                                       \
          float h0 = fmaxf(ac[t][0], 0.f) + 0.01f * nzv[t].x;                  \
          float h1 = fmaxf(ac[t][1], 0.f) + 0.01f * nzv[t].y;                  \
          float h2 = fmaxf(ac[t][2], 0.f) + 0.01f * nzv[t].z;                  \
          float h3 = fmaxf(ac[t][3], 0.f) + 0.01f * nzv[t].w;                  \
          uint2 pk; pk.x = cvt_pk_bf16(h0, h1); pk.y = cvt_pk_bf16(h2, h3);    \
          *(uint2*)&Abuf[(CUR) ^ 1][lc][cbt] = pk;                             \
        }                                                                      \
      }                                                                        \
    } }                                                                        \
    if (DO_X) { if (xw) {                                                      \
      *(uint32_t*)&Abuf[(CUR) ^ 1][lc][300] = cvt_pk_bf16(xvh.x, xvh.y);       \
    } }                                                                        \
    if (DO_EPI) STEP_BARRIER();                                                \
  }

  // peeled first block (S=0..5): no out-write at S=0
  STEPM(0, 0, 0, 2, 0, 1, 1, 1, 1);
  STEPM(1, 1, 1, 0, 1, 1, 1, 1, 1);
  STEPM(2, 0, 2, 1, 1, 1, 1, 1, 1);
  STEPM(3, 1, 0, 2, 1, 1, 1, 1, 1);
  STEPM(4, 0, 1, 0, 1, 1, 1, 1, 1);
  STEPM(5, 1, 2, 1, 1, 1, 1, 1, 1);

  // main: S = 6..119 (19 blocks of 6; all guards statically true)
  for (int s = 6; s < 120; s += 6) {
    STEPM(s + 0, 0, 0, 2, 1, 1, 1, 1, 1);
    STEPM(s + 1, 1, 1, 0, 1, 1, 1, 1, 1);
    STEPM(s + 2, 0, 2, 1, 1, 1, 1, 1, 1);
    STEPM(s + 3, 1, 0, 2, 1, 1, 1, 1, 1);
    STEPM(s + 4, 0, 1, 0, 1, 1, 1, 1, 1);
    STEPM(s + 5, 1, 2, 1, 1, 1, 1, 1, 1);
  }

  // tail S=120..125 (slab-124 re-issues keep per-wave vmcnt uniform)
  STEPM(120, 0, 0, 2, 1, 1, 1, 1, 1);
  STEPM(121, 1, 1, 0, 1, 1, 1, 1, 1);
  STEPM(122, 0, 2, 1, 1, 1, 1, 0, 1);  // issues slab 124; stop advancing
  STEPM(123, 1, 0, 2, 1, 1, 1, 0, 1);  // re-issue (dead buffer)
  STEPM(124, 0, 1, 0, 1, 1, 0, 0, 1);  // no x_125; re-issue (dead buffer)
  STEPM(125, 1, 2, 1, 1, 0, 0, 0, 0);  // MFMA + out[124] only, no barrier

#undef STEPM

  __syncthreads();  // full drain; outbuf visible

  // coalesced flush
  for (int i = tid; i < RPW * SEQ * 2; i += NTH) {
    int r = i / (SEQ * 2), j = i % (SEQ * 2);
    out[(row0 + r) * (SEQ * 2) + j] = outbuf[r][j];
  }
}

extern "C" void kernel_launch(void* const* d_in, const int* in_sizes, int n_in,
                              void* d_out, int out_size, void* d_ws, size_t ws_size,
                              hipStream_t stream) {
  const float* xp     = (const float*)d_in[0];
  const float* noise  = (const float*)d_in[1];
  const float* W_ih   = (const float*)d_in[2];
  const float* b_ih   = (const float*)d_in[3];
  const float* W_hh   = (const float*)d_in[4];
  const float* b_hh   = (const float*)d_in[5];
  const float* W_out  = (const float*)d_in[6];
  const float* b_out  = (const float*)d_in[7];
  float* outp         = (float*)d_out;

  rnn_fused<<<dim3(2048 / RPW), dim3(NTH), 0, stream>>>(
      xp, noise, W_ih, b_ih, W_hh, b_hh, W_out, b_out, outp);
}

// Round 16
// 153.135 us; speedup vs baseline: 2.1133x; 2.1133x over previous
//
#include <hip/hip_runtime.h>
#include <stdint.h>

// VanillaRNN fused: B=2048,S=125,I=2,H=300,O=2
// h_t = relu(x_t@W_ih^T + b_ih + h_{t-1}@W_hh^T + b_hh) + 0.01*noise_t
// out = h_t @ W_out^T + b_out
//
// R16 = R13 (139.5us: swapped MFMA A=W-in-regs / B=h-from-LDS, x/bias
// folded as K-rows 300-302, W_out as cols 300/301, Nbuf noise DMA
// triple-buffered 2 steps ahead, vmcnt(1) single-asm barrier, zero-row
// Abuf, named A-frag preload, 6-period static unroll) plus:
//  - NBUF TRANSPOSED-SWIZZLE (m173 pattern): global_load_lds dest stays
//    wave-linear (slot = tid), but the per-lane SOURCE is permuted so
//    slot tid holds chunk (row = tid&7, cc = tid>>3). Epilogue read
//    slot = 64w+8g+lc -> 32 active lanes hit 32 DISTINCT banksets
//    (zero conflict; was 3-way). DMA still coalesces as 8x128B/wave.
//  - s_setprio(1) around the MFMA block (T5: waves are role-diverse).
// R15's 1-wave/SIMD regime REVERTED (no TLP -> 323us).

#define SEQ   125
#define HID   300
#define APAD  328     // Abuf row stride in shorts; A-reads are <=2-way (free)
#define KT    10
#define WAVES 10
#define NTH   (WAVES * 64)
#define RPW   8
#define NCH   600     // 16B chunks per step-slab (8*300*4B/16)
#define NSLAB 2408    // floats per Nbuf slab (2400 + 8 pad)

typedef __attribute__((ext_vector_type(8))) short bf16x8;
typedef __attribute__((ext_vector_type(4))) float f32x4;

__device__ __forceinline__ short f2bf(float f) {
  union { float f; uint32_t u; } v; v.f = f;
  uint32_t r = (v.u + 0x7fffu + ((v.u >> 16) & 1u)) >> 16;  // RNE
  return (short)r;
}

__device__ __forceinline__ uint32_t cvt_pk_bf16(float lo, float hi) {
  uint32_t r;
  asm("v_cvt_pk_bf16_f32 %0, %1, %2" : "=v"(r) : "v"(lo), "v"(hi));
  return r;
}

__device__ __forceinline__ void dma16(const float* g, float* l) {
  __builtin_amdgcn_global_load_lds(
      (const __attribute__((address_space(1))) unsigned int*)g,
      (__attribute__((address_space(3))) unsigned int*)l, 16, 0, 0);
}

// Single-asm counted barrier: vmcnt(1) -> older of the 2 in-flight noise
// DMAs has landed; newer stays in flight across the barrier. lgkmcnt(0)
// -> own ds reads/writes done. One asm block = no hoisting window.
#define STEP_BARRIER() \
  asm volatile("s_waitcnt vmcnt(1) lgkmcnt(0)\n\ts_barrier" ::: "memory")

__global__ __launch_bounds__(NTH)
__attribute__((amdgpu_waves_per_eu(3, 3)))
void rnn_fused(
    const float* __restrict__ x,      // [2048,125,2]
    const float* __restrict__ noise,  // [2048,125,300]
    const float* __restrict__ W_ih,   // [300,2]
    const float* __restrict__ b_ih,   // [300]
    const float* __restrict__ W_hh,   // [300,300]
    const float* __restrict__ b_hh,   // [300]
    const float* __restrict__ W_out,  // [2,300]
    const float* __restrict__ b_out,  // [2]
    float* __restrict__ out)          // [2048,125,2]
{
  // rows 0..7 = batch rows' h (+x cols 300-301, bias col 302); row 8 = zeros
  __shared__ __align__(16) short Abuf[2][9][APAD];   // 11808 B
  __shared__ __align__(16) float Nbuf[3][NSLAB];     // 28896 B noise 3-buf
  __shared__ float xbuf[RPW][SEQ * 2];               //  8000 B
  __shared__ float outbuf[RPW][SEQ * 2];             //  8000 B

  const int tid  = threadIdx.x;
  const int wave = tid >> 6;
  const int lane = tid & 63;
  const int grp  = lane >> 4;     // 0..3
  const int lc   = lane & 15;     // 0..15
  const int row0 = blockIdx.x * RPW;
  const int grp8 = grp * 8;
  const int arow = (lc < 8) ? lc : 8;     // zero-row broadcast
  const bool lcr = (lc < 8);              // lane's batch row is real
  const bool w9  = (wave == 9);
  const int cb0  = wave * 32 + grp * 4;   // tile0 output-col base
  // transposed-swizzle Nbuf read: slot = 64w+8g+lc (32 distinct banksets)
  const int nb0  = (wave * 64 + grp * 8 + lc) * 4;  // float index, tile0

  // zero both Abuf buffers (incl. zero-row + cols 302..327)
  for (int i = tid; i < 2 * 9 * APAD / 2; i += NTH)
    ((uint32_t*)Abuf)[i] = 0u;
  // stage x
  for (int i = tid; i < RPW * SEQ * 2; i += NTH) {
    int r = i / (SEQ * 2), j = i % (SEQ * 2);
    xbuf[r][j] = x[(row0 + r) * (SEQ * 2) + j];
  }

  const float bout0 = b_out[0], bout1 = b_out[1];

  // ---- persistent A-side fragments: wf[t][kt], lane holds W for col
  // c = wave*32 + t*16 + lc, k = kt*32 + grp*8 + e.
  // k=300/301: W_ih cols; k=302: b_ih+b_hh; c=300/301: W_out rows (k<300).
  bf16x8 wf0[KT], wf1[KT];
#pragma unroll
  for (int t = 0; t < 2; ++t) {
    int c = wave * 32 + t * 16 + lc;
#pragma unroll
    for (int kt = 0; kt < KT; ++kt) {
      bf16x8 f;
#pragma unroll
      for (int e = 0; e < 8; ++e) {
        int k = kt * 32 + grp8 + e;
        float v = 0.f;
        if (c < HID) {
          if (k < HID)            v = W_hh[c * HID + k];
          else if (k == HID)      v = W_ih[c * 2 + 0];
          else if (k == HID + 1)  v = W_ih[c * 2 + 1];
          else if (k == HID + 2)  v = b_ih[c] + b_hh[c];
        } else if (c == HID) {
          if (k < HID)            v = W_out[k];
        } else if (c == HID + 1) {
          if (k < HID)            v = W_out[HID + k];
        }
        f[e] = f2bf(v);
      }
      if (t == 0) wf0[kt] = f; else wf1[kt] = f;
    }
  }

  // ---- noise DMA with transposed-swizzle SOURCE: slot tid holds chunk
  // (row = tid&7, chunkcol = tid>>3). Dest stays wave-linear.
  const bool dma = (tid < NCH);
  const float* gsrc = dma
      ? noise + (size_t)(row0 + (tid & 7)) * (SEQ * HID) + ((tid >> 3) << 2)
      : noise;

  __syncthreads();  // Abuf zeros + xbuf visible

  // post-zero init: x_0 into Abuf[0] cols 300-301; bias-one col 302 (both)
  if (tid < 8) {
    float2 xv = *(const float2*)&x[(size_t)(row0 + tid) * (SEQ * 2)];
    *(uint32_t*)&Abuf[0][tid][300] = cvt_pk_bf16(xv.x, xv.y);
    Abuf[0][tid][302] = (short)0x3F80;   // bf16 1.0
    Abuf[1][tid][302] = (short)0x3F80;
  }

  // prologue DMA: slabs 0 and 1
  if (dma) {
    dma16(gsrc, &Nbuf[0][wave * 256]);
    dma16(gsrc + HID, &Nbuf[1][wave * 256]);
  }
  const float* gsrc2 = gsrc + 2 * HID;
  STEP_BARRIER();  // slab 0 landed; slab 1 in flight; init LDS visible

  const bool xw = (wave == 0) && (grp == 0) && lcr;  // lanes 0-7

  // Iteration S: MFMA on Abuf[CUR] (= h_{S-1} + x_S + bias); out[S-1]
  // from cols 300/301 (S>=1); epilogue writes h_S + x_{S+1} (S<SEQ).
#define STEPM(S, CUR, RB, WB, DO_OUT, DO_EPI, DO_X, DO_ADV, DO_DMA)            \
  {                                                                            \
    if (DO_DMA) { if (dma) dma16(gsrc2, &Nbuf[WB][wave * 256]); }              \
    if (DO_ADV) gsrc2 += HID;                                                  \
    const short* Ab = &Abuf[CUR][arow][grp8];                                  \
    /* full A-frag preload: all 10 reads enter the LDS queue up front */       \
    bf16x8 h0 = *(const bf16x8*)(Ab + 0);                                      \
    bf16x8 h1 = *(const bf16x8*)(Ab + 32);                                     \
    bf16x8 h2 = *(const bf16x8*)(Ab + 64);                                     \
    bf16x8 h3 = *(const bf16x8*)(Ab + 96);                                     \
    bf16x8 h4 = *(const bf16x8*)(Ab + 128);                                    \
    bf16x8 h5 = *(const bf16x8*)(Ab + 160);                                    \
    bf16x8 h6 = *(const bf16x8*)(Ab + 192);                                    \
    bf16x8 h7 = *(const bf16x8*)(Ab + 224);                                    \
    bf16x8 h8 = *(const bf16x8*)(Ab + 256);                                    \
    bf16x8 h9 = *(const bf16x8*)(Ab + 288);                                    \
    __builtin_amdgcn_s_setprio(1);                                             \
    f32x4 t0a = {0.f,0.f,0.f,0.f}, t0b = {0.f,0.f,0.f,0.f};                    \
    f32x4 t1a = {0.f,0.f,0.f,0.f}, t1b = {0.f,0.f,0.f,0.f};                    \
    t0a = __builtin_amdgcn_mfma_f32_16x16x32_bf16(wf0[0], h0, t0a, 0,0,0);     \
    t1a = __builtin_amdgcn_mfma_f32_16x16x32_bf16(wf1[0], h0, t1a, 0,0,0);     \
    t0b = __builtin_amdgcn_mfma_f32_16x16x32_bf16(wf0[1], h1, t0b, 0,0,0);     \
    t1b = __builtin_amdgcn_mfma_f32_16x16x32_bf16(wf1[1], h1, t1b, 0,0,0);     \
    t0a = __builtin_amdgcn_mfma_f32_16x16x32_bf16(wf0[2], h2, t0a, 0,0,0);     \
    t1a = __builtin_amdgcn_mfma_f32_16x16x32_bf16(wf1[2], h2, t1a, 0,0,0);     \
    t0b = __builtin_amdgcn_mfma_f32_16x16x32_bf16(wf0[3], h3, t0b, 0,0,0);     \
    t1b = __builtin_amdgcn_mfma_f32_16x16x32_bf16(wf1[3], h3, t1b, 0,0,0);     \
    t0a = __builtin_amdgcn_mfma_f32_16x16x32_bf16(wf0[4], h4, t0a, 0,0,0);     \
    t1a = __builtin_amdgcn_mfma_f32_16x16x32_bf16(wf1[4], h4, t1a, 0,0,0);     \
    t0b = __builtin_amdgcn_mfma_f32_16x16x32_bf16(wf0[5], h5, t0b, 0,0,0);     \
    t1b = __builtin_amdgcn_mfma_f32_16x16x32_bf16(wf1[5], h5, t1b, 0,0,0);     \
    t0a = __builtin_amdgcn_mfma_f32_16x16x32_bf16(wf0[6], h6, t0a, 0,0,0);     \
    t1a = __builtin_amdgcn_mfma_f32_16x16x32_bf16(wf1[6], h6, t1a, 0,0,0);     \
    t0b = __builtin_amdgcn_mfma_f32_16x16x32_bf16(wf0[7], h7, t0b, 0,0,0);     \
    t1b = __builtin_amdgcn_mfma_f32_16x16x32_bf16(wf1[7], h7, t1b, 0,0,0);     \
    t0a = __builtin_amdgcn_mfma_f32_16x16x32_bf16(wf0[8], h8, t0a, 0,0,0);     \
    t1a = __builtin_amdgcn_mfma_f32_16x16x32_bf16(wf1[8], h8, t1a, 0,0,0);     \
    t0b = __builtin_amdgcn_mfma_f32_16x16x32_bf16(wf0[9], h9, t0b, 0,0,0);     \
    t1b = __builtin_amdgcn_mfma_f32_16x16x32_bf16(wf1[9], h9, t1b, 0,0,0);     \
    __builtin_amdgcn_s_setprio(0);                                             \
    f32x4 ac0 = t0a + t0b, ac1 = t1a + t1b;                                    \
    if (w9) {                                                                  \
      if (DO_OUT) { if (grp == 3 && lcr) {                                     \
        float2 o; o.x = ac0[0] + bout0; o.y = ac0[1] + bout1;                  \
        *(float2*)&outbuf[lc][((S) - 1) * 2] = o;                              \
      } }                                                                      \
      if (DO_EPI) { if (lcr && grp < 3) {                                      \
        float4 nz = *(const float4*)&Nbuf[RB][nb0];                            \
        float h0v = fmaxf(ac0[0], 0.f) + 0.01f * nz.x;                         \
        float h1v = fmaxf(ac0[1], 0.f) + 0.01f * nz.y;                         \
        float h2v = fmaxf(ac0[2], 0.f) + 0.01f * nz.z;                         \
        float h3v = fmaxf(ac0[3], 0.f) + 0.01f * nz.w;                         \
        uint2 pk; pk.x = cvt_pk_bf16(h0v, h1v); pk.y = cvt_pk_bf16(h2v, h3v);  \
        *(uint2*)&Abuf[(CUR) ^ 1][lc][cb0] = pk;                               \
      } }                                                                      \
    } else {                                                                   \
      if (DO_EPI) { if (lcr) {                                                 \
        float4 nz0 = *(const float4*)&Nbuf[RB][nb0];                           \
        float4 nz1 = *(const float4*)&Nbuf[RB][nb0 + 128];                     \
        float a0 = fmaxf(ac0[0], 0.f) + 0.01f * nz0.x;                         \
        float a1 = fmaxf(ac0[1], 0.f) + 0.01f * nz0.y;                         \
        float a2 = fmaxf(ac0[2], 0.f) + 0.01f * nz0.z;                         \
        float a3 = fmaxf(ac0[3], 0.f) + 0.01f * nz0.w;                         \
        float b0 = fmaxf(ac1[0], 0.f) + 0.01f * nz1.x;                         \
        float b1 = fmaxf(ac1[1], 0.f) + 0.01f * nz1.y;                         \
        float b2 = fmaxf(ac1[2], 0.f) + 0.01f * nz1.z;                         \
        float b3 = fmaxf(ac1[3], 0.f) + 0.01f * nz1.w;                         \
        uint2 p0; p0.x = cvt_pk_bf16(a0, a1); p0.y = cvt_pk_bf16(a2, a3);      \
        uint2 p1; p1.x = cvt_pk_bf16(b0, b1); p1.y = cvt_pk_bf16(b2, b3);      \
        *(uint2*)&Abuf[(CUR) ^ 1][lc][cb0] = p0;                               \
        *(uint2*)&Abuf[(CUR) ^ 1][lc][cb0 + 16] = p1;                          \
      } }                                                                      \
    }                                                                          \
    if (DO_X) { if (xw) {                                                      \
      float2 xv = *(const float2*)&xbuf[lc][((S) + 1) * 2];                    \
      *(uint32_t*)&Abuf[(CUR) ^ 1][lc][300] = cvt_pk_bf16(xv.x, xv.y);         \
    } }                                                                        \
    if (DO_EPI) STEP_BARRIER();                                                \
  }

  // peeled first block (S=0..5): no out-write at S=0
  STEPM(0, 0, 0, 2, 0, 1, 1, 1, 1);
  STEPM(1, 1, 1, 0, 1, 1, 1, 1, 1);
  STEPM(2, 0, 2, 1, 1, 1, 1, 1, 1);
  STEPM(3, 1, 0, 2, 1, 1, 1, 1, 1);
  STEPM(4, 0, 1, 0, 1, 1, 1, 1, 1);
  STEPM(5, 1, 2, 1, 1, 1, 1, 1, 1);

  // main: S = 6..119 (19 blocks of 6; all guards statically true)
  for (int s = 6; s < 120; s += 6) {
    STEPM(s + 0, 0, 0, 2, 1, 1, 1, 1, 1);
    STEPM(s + 1, 1, 1, 0, 1, 1, 1, 1, 1);
    STEPM(s + 2, 0, 2, 1, 1, 1, 1, 1, 1);
    STEPM(s + 3, 1, 0, 2, 1, 1, 1, 1, 1);
    STEPM(s + 4, 0, 1, 0, 1, 1, 1, 1, 1);
    STEPM(s + 5, 1, 2, 1, 1, 1, 1, 1, 1);
  }

  // tail S=120..125 (static guards; slab-124 re-issues keep vmcnt uniform)
  STEPM(120, 0, 0, 2, 1, 1, 1, 1, 1);
  STEPM(121, 1, 1, 0, 1, 1, 1, 1, 1);
  STEPM(122, 0, 2, 1, 1, 1, 1, 0, 1);  // no more advance (slab 124 is last)
  STEPM(123, 1, 0, 2, 1, 1, 1, 0, 1);
  STEPM(124, 0, 1, 0, 1, 1, 0, 0, 1);  // no x_125
  STEPM(125, 1, 2, 1, 1, 0, 0, 0, 0);  // MFMA + out[124] only, no barrier

#undef STEPM

  __syncthreads();  // full drain; outbuf visible

  // coalesced flush
  for (int i = tid; i < RPW * SEQ * 2; i += NTH) {
    int r = i / (SEQ * 2), j = i % (SEQ * 2);
    out[(row0 + r) * (SEQ * 2) + j] = outbuf[r][j];
  }
}

extern "C" void kernel_launch(void* const* d_in, const int* in_sizes, int n_in,
                              void* d_out, int out_size, void* d_ws, size_t ws_size,
                              hipStream_t stream) {
  const float* xp     = (const float*)d_in[0];
  const float* noise  = (const float*)d_in[1];
  const float* W_ih   = (const float*)d_in[2];
  const float* b_ih   = (const float*)d_in[3];
  const float* W_hh   = (const float*)d_in[4];
  const float* b_hh   = (const float*)d_in[5];
  const float* W_out  = (const float*)d_in[6];
  const float* b_out  = (const float*)d_in[7];
  float* outp         = (float*)d_out;

  rnn_fused<<<dim3(2048 / RPW), dim3(NTH), 0, stream>>>(
      xp, noise, W_ih, b_ih, W_hh, b_hh, W_out, b_out, outp);
}

// Round 17
// 139.305 us; speedup vs baseline: 2.3231x; 1.0993x over previous
//
#include <hip/hip_runtime.h>
#include <stdint.h>

// VanillaRNN fused: B=2048,S=125,I=2,H=300,O=2
// h_t = relu(x_t@W_ih^T + b_ih + h_{t-1}@W_hh^T + b_hh) + 0.01*noise_t
// out = h_t @ W_out^T + b_out
//
// R17 = R13 (139.5us: swapped MFMA A=W-in-regs / B=h-from-LDS, x/bias
// folded as K-rows 300-302, W_out as cols 300/301, Nbuf noise DMA
// triple-buffered 2 steps ahead, vmcnt(1) single-asm barrier, zero-row
// Abuf, named A-frag preload, 6-period static unroll)
// + Nbuf TRANSPOSED-SWIZZLE only (register-neutral, -1.2e6 conflicts):
//   global_load_lds dest stays wave-linear (slot=tid); per-lane SOURCE
//   permuted so slot tid holds chunk (row=tid&7, cc=tid>>3); epilogue
//   read slot = 64w+8g+lc -> conflict-free, and the address math is
//   cheaper than lc*300+cb0.
// R16's s_setprio REMOVED: it fences the scheduler, forcing all 10
// h-frags + 16 acc live at once -> spill (WRITE_SIZE 7.8->30.8MB, the
// R8/R14 failure mode via a different mechanism).

#define SEQ   125
#define HID   300
#define APAD  328     // Abuf row stride in shorts
#define KT    10
#define WAVES 10
#define NTH   (WAVES * 64)
#define RPW   8
#define NCH   600     // 16B chunks per step-slab (8*300*4B/16)
#define NSLAB 2408    // floats per Nbuf slab (2400 + 8 pad)

typedef __attribute__((ext_vector_type(8))) short bf16x8;
typedef __attribute__((ext_vector_type(4))) float f32x4;

__device__ __forceinline__ short f2bf(float f) {
  union { float f; uint32_t u; } v; v.f = f;
  uint32_t r = (v.u + 0x7fffu + ((v.u >> 16) & 1u)) >> 16;  // RNE
  return (short)r;
}

__device__ __forceinline__ uint32_t cvt_pk_bf16(float lo, float hi) {
  uint32_t r;
  asm("v_cvt_pk_bf16_f32 %0, %1, %2" : "=v"(r) : "v"(lo), "v"(hi));
  return r;
}

__device__ __forceinline__ void dma16(const float* g, float* l) {
  __builtin_amdgcn_global_load_lds(
      (const __attribute__((address_space(1))) unsigned int*)g,
      (__attribute__((address_space(3))) unsigned int*)l, 16, 0, 0);
}

// Single-asm counted barrier: vmcnt(1) -> older of the 2 in-flight noise
// DMAs has landed; newer stays in flight across the barrier. lgkmcnt(0)
// -> own ds reads/writes done. One asm block = no hoisting window.
#define STEP_BARRIER() \
  asm volatile("s_waitcnt vmcnt(1) lgkmcnt(0)\n\ts_barrier" ::: "memory")

__global__ __launch_bounds__(NTH)
__attribute__((amdgpu_waves_per_eu(3, 3)))
void rnn_fused(
    const float* __restrict__ x,      // [2048,125,2]
    const float* __restrict__ noise,  // [2048,125,300]
    const float* __restrict__ W_ih,   // [300,2]
    const float* __restrict__ b_ih,   // [300]
    const float* __restrict__ W_hh,   // [300,300]
    const float* __restrict__ b_hh,   // [300]
    const float* __restrict__ W_out,  // [2,300]
    const float* __restrict__ b_out,  // [2]
    float* __restrict__ out)          // [2048,125,2]
{
  // rows 0..7 = batch rows' h (+x cols 300-301, bias col 302); row 8 = zeros
  __shared__ __align__(16) short Abuf[2][9][APAD];   // 11808 B
  __shared__ __align__(16) float Nbuf[3][NSLAB];     // 28896 B noise 3-buf
  __shared__ float xbuf[RPW][SEQ * 2];               //  8000 B
  __shared__ float outbuf[RPW][SEQ * 2];             //  8000 B

  const int tid  = threadIdx.x;
  const int wave = tid >> 6;
  const int lane = tid & 63;
  const int grp  = lane >> 4;     // 0..3
  const int lc   = lane & 15;     // 0..15
  const int row0 = blockIdx.x * RPW;
  const int grp8 = grp * 8;
  const int arow = (lc < 8) ? lc : 8;     // zero-row broadcast
  const bool lcr = (lc < 8);              // lane's batch row is real
  const bool w9  = (wave == 9);
  const int cb0  = wave * 32 + grp * 4;   // tile0 output-col base
  // transposed-swizzle Nbuf read: slot = 64w+8g+lc -> conflict-free
  const int nb0  = (wave * 64 + grp * 8 + lc) * 4;  // float index, tile0

  // zero both Abuf buffers (incl. zero-row + cols 302..327)
  for (int i = tid; i < 2 * 9 * APAD / 2; i += NTH)
    ((uint32_t*)Abuf)[i] = 0u;
  // stage x
  for (int i = tid; i < RPW * SEQ * 2; i += NTH) {
    int r = i / (SEQ * 2), j = i % (SEQ * 2);
    xbuf[r][j] = x[(row0 + r) * (SEQ * 2) + j];
  }

  const float bout0 = b_out[0], bout1 = b_out[1];

  // ---- persistent A-side fragments: wf[t][kt], lane holds W for col
  // c = wave*32 + t*16 + lc, k = kt*32 + grp*8 + e.
  // k=300/301: W_ih cols; k=302: b_ih+b_hh; c=300/301: W_out rows (k<300).
  bf16x8 wf0[KT], wf1[KT];
#pragma unroll
  for (int t = 0; t < 2; ++t) {
    int c = wave * 32 + t * 16 + lc;
#pragma unroll
    for (int kt = 0; kt < KT; ++kt) {
      bf16x8 f;
#pragma unroll
      for (int e = 0; e < 8; ++e) {
        int k = kt * 32 + grp8 + e;
        float v = 0.f;
        if (c < HID) {
          if (k < HID)            v = W_hh[c * HID + k];
          else if (k == HID)      v = W_ih[c * 2 + 0];
          else if (k == HID + 1)  v = W_ih[c * 2 + 1];
          else if (k == HID + 2)  v = b_ih[c] + b_hh[c];
        } else if (c == HID) {
          if (k < HID)            v = W_out[k];
        } else if (c == HID + 1) {
          if (k < HID)            v = W_out[HID + k];
        }
        f[e] = f2bf(v);
      }
      if (t == 0) wf0[kt] = f; else wf1[kt] = f;
    }
  }

  // ---- noise DMA with transposed-swizzle SOURCE: slot tid holds chunk
  // (row = tid&7, chunkcol = tid>>3). Dest stays wave-linear.
  const bool dma = (tid < NCH);
  const float* gsrc = dma
      ? noise + (size_t)(row0 + (tid & 7)) * (SEQ * HID) + ((tid >> 3) << 2)
      : noise;

  __syncthreads();  // Abuf zeros + xbuf visible

  // post-zero init: x_0 into Abuf[0] cols 300-301; bias-one col 302 (both)
  if (tid < 8) {
    float2 xv = *(const float2*)&x[(size_t)(row0 + tid) * (SEQ * 2)];
    *(uint32_t*)&Abuf[0][tid][300] = cvt_pk_bf16(xv.x, xv.y);
    Abuf[0][tid][302] = (short)0x3F80;   // bf16 1.0
    Abuf[1][tid][302] = (short)0x3F80;
  }

  // prologue DMA: slabs 0 and 1
  if (dma) {
    dma16(gsrc, &Nbuf[0][wave * 256]);
    dma16(gsrc + HID, &Nbuf[1][wave * 256]);
  }
  const float* gsrc2 = gsrc + 2 * HID;
  STEP_BARRIER();  // slab 0 landed; slab 1 in flight; init LDS visible

  const bool xw = (wave == 0) && (grp == 0) && lcr;  // lanes 0-7

  // Iteration S: MFMA on Abuf[CUR] (= h_{S-1} + x_S + bias); out[S-1]
  // from cols 300/301 (S>=1); epilogue writes h_S + x_{S+1} (S<SEQ).
#define STEPM(S, CUR, RB, WB, DO_OUT, DO_EPI, DO_X, DO_ADV, DO_DMA)            \
  {                                                                            \
    if (DO_DMA) { if (dma) dma16(gsrc2, &Nbuf[WB][wave * 256]); }              \
    if (DO_ADV) gsrc2 += HID;                                                  \
    const short* Ab = &Abuf[CUR][arow][grp8];                                  \
    /* full A-frag preload: all 10 reads enter the LDS queue up front */       \
    bf16x8 h0 = *(const bf16x8*)(Ab + 0);                                      \
    bf16x8 h1 = *(const bf16x8*)(Ab + 32);                                     \
    bf16x8 h2 = *(const bf16x8*)(Ab + 64);                                     \
    bf16x8 h3 = *(const bf16x8*)(Ab + 96);                                     \
    bf16x8 h4 = *(const bf16x8*)(Ab + 128);                                    \
    bf16x8 h5 = *(const bf16x8*)(Ab + 160);                                    \
    bf16x8 h6 = *(const bf16x8*)(Ab + 192);                                    \
    bf16x8 h7 = *(const bf16x8*)(Ab + 224);                                    \
    bf16x8 h8 = *(const bf16x8*)(Ab + 256);                                    \
    bf16x8 h9 = *(const bf16x8*)(Ab + 288);                                    \
    f32x4 t0a = {0.f,0.f,0.f,0.f}, t0b = {0.f,0.f,0.f,0.f};                    \
    f32x4 t1a = {0.f,0.f,0.f,0.f}, t1b = {0.f,0.f,0.f,0.f};                    \
    t0a = __builtin_amdgcn_mfma_f32_16x16x32_bf16(wf0[0], h0, t0a, 0,0,0);     \
    t1a = __builtin_amdgcn_mfma_f32_16x16x32_bf16(wf1[0], h0, t1a, 0,0,0);     \
    t0b = __builtin_amdgcn_mfma_f32_16x16x32_bf16(wf0[1], h1, t0b, 0,0,0);     \
    t1b = __builtin_amdgcn_mfma_f32_16x16x32_bf16(wf1[1], h1, t1b, 0,0,0);     \
    t0a = __builtin_amdgcn_mfma_f32_16x16x32_bf16(wf0[2], h2, t0a, 0,0,0);     \
    t1a = __builtin_amdgcn_mfma_f32_16x16x32_bf16(wf1[2], h2, t1a, 0,0,0);     \
    t0b = __builtin_amdgcn_mfma_f32_16x16x32_bf16(wf0[3], h3, t0b, 0,0,0);     \
    t1b = __builtin_amdgcn_mfma_f32_16x16x32_bf16(wf1[3], h3, t1b, 0,0,0);     \
    t0a = __builtin_amdgcn_mfma_f32_16x16x32_bf16(wf0[4], h4, t0a, 0,0,0);     \
    t1a = __builtin_amdgcn_mfma_f32_16x16x32_bf16(wf1[4], h4, t1a, 0,0,0);     \
    t0b = __builtin_amdgcn_mfma_f32_16x16x32_bf16(wf0[5], h5, t0b, 0,0,0);     \
    t1b = __builtin_amdgcn_mfma_f32_16x16x32_bf16(wf1[5], h5, t1b, 0,0,0);     \
    t0a = __builtin_amdgcn_mfma_f32_16x16x32_bf16(wf0[6], h6, t0a, 0,0,0);     \
    t1a = __builtin_amdgcn_mfma_f32_16x16x32_bf16(wf1[6], h6, t1a, 0,0,0);     \
    t0b = __builtin_amdgcn_mfma_f32_16x16x32_bf16(wf0[7], h7, t0b, 0,0,0);     \
    t1b = __builtin_amdgcn_mfma_f32_16x16x32_bf16(wf1[7], h7, t1b, 0,0,0);     \
    t0a = __builtin_amdgcn_mfma_f32_16x16x32_bf16(wf0[8], h8, t0a, 0,0,0);     \
    t1a = __builtin_amdgcn_mfma_f32_16x16x32_bf16(wf1[8], h8, t1a, 0,0,0);     \
    t0b = __builtin_amdgcn_mfma_f32_16x16x32_bf16(wf0[9], h9, t0b, 0,0,0);     \
    t1b = __builtin_amdgcn_mfma_f32_16x16x32_bf16(wf1[9], h9, t1b, 0,0,0);     \
    f32x4 ac0 = t0a + t0b, ac1 = t1a + t1b;                                    \
    if (w9) {                                                                  \
      if (DO_OUT) { if (grp == 3 && lcr) {                                     \
        float2 o; o.x = ac0[0] + bout0; o.y = ac0[1] + bout1;                  \
        *(float2*)&outbuf[lc][((S) - 1) * 2] = o;                              \
      } }                                                                      \
      if (DO_EPI) { if (lcr && grp < 3) {                                      \
        float4 nz = *(const float4*)&Nbuf[RB][nb0];                            \
        float h0v = fmaxf(ac0[0], 0.f) + 0.01f * nz.x;                         \
        float h1v = fmaxf(ac0[1], 0.f) + 0.01f * nz.y;                         \
        float h2v = fmaxf(ac0[2], 0.f) + 0.01f * nz.z;                         \
        float h3v = fmaxf(ac0[3], 0.f) + 0.01f * nz.w;                         \
        uint2 pk; pk.x = cvt_pk_bf16(h0v, h1v); pk.y = cvt_pk_bf16(h2v, h3v);  \
        *(uint2*)&Abuf[(CUR) ^ 1][lc][cb0] = pk;                               \
      } }                                                                      \
    } else {                                                                   \
      if (DO_EPI) { if (lcr) {                                                 \
        float4 nz0 = *(const float4*)&Nbuf[RB][nb0];                           \
        float4 nz1 = *(const float4*)&Nbuf[RB][nb0 + 128];                     \
        float a0 = fmaxf(ac0[0], 0.f) + 0.01f * nz0.x;                         \
        float a1 = fmaxf(ac0[1], 0.f) + 0.01f * nz0.y;                         \
        float a2 = fmaxf(ac0[2], 0.f) + 0.01f * nz0.z;                         \
        float a3 = fmaxf(ac0[3], 0.f) + 0.01f * nz0.w;                         \
        float b0 = fmaxf(ac1[0], 0.f) + 0.01f * nz1.x;                         \
        float b1 = fmaxf(ac1[1], 0.f) + 0.01f * nz1.y;                         \
        float b2 = fmaxf(ac1[2], 0.f) + 0.01f * nz1.z;                         \
        float b3 = fmaxf(ac1[3], 0.f) + 0.01f * nz1.w;                         \
        uint2 p0; p0.x = cvt_pk_bf16(a0, a1); p0.y = cvt_pk_bf16(a2, a3);      \
        uint2 p1; p1.x = cvt_pk_bf16(b0, b1); p1.y = cvt_pk_bf16(b2, b3);      \
        *(uint2*)&Abuf[(CUR) ^ 1][lc][cb0] = p0;                               \
        *(uint2*)&Abuf[(CUR) ^ 1][lc][cb0 + 16] = p1;                          \
      } }                                                                      \
    }                                                                          \
    if (DO_X) { if (xw) {                                                      \
      float2 xv = *(const float2*)&xbuf[lc][((S) + 1) * 2];                    \
      *(uint32_t*)&Abuf[(CUR) ^ 1][lc][300] = cvt_pk_bf16(xv.x, xv.y);         \
    } }                                                                        \
    if (DO_EPI) STEP_BARRIER();                                                \
  }

  // peeled first block (S=0..5): no out-write at S=0
  STEPM(0, 0, 0, 2, 0, 1, 1, 1, 1);
  STEPM(1, 1, 1, 0, 1, 1, 1, 1, 1);
  STEPM(2, 0, 2, 1, 1, 1, 1, 1, 1);
  STEPM(3, 1, 0, 2, 1, 1, 1, 1, 1);
  STEPM(4, 0, 1, 0, 1, 1, 1, 1, 1);
  STEPM(5, 1, 2, 1, 1, 1, 1, 1, 1);

  // main: S = 6..119 (19 blocks of 6; all guards statically true)
  for (int s = 6; s < 120; s += 6) {
    STEPM(s + 0, 0, 0, 2, 1, 1, 1, 1, 1);
    STEPM(s + 1, 1, 1, 0, 1, 1, 1, 1, 1);
    STEPM(s + 2, 0, 2, 1, 1, 1, 1, 1, 1);
    STEPM(s + 3, 1, 0, 2, 1, 1, 1, 1, 1);
    STEPM(s + 4, 0, 1, 0, 1, 1, 1, 1, 1);
    STEPM(s + 5, 1, 2, 1, 1, 1, 1, 1, 1);
  }

  // tail S=120..125 (static guards; slab-124 re-issues keep vmcnt uniform)
  STEPM(120, 0, 0, 2, 1, 1, 1, 1, 1);
  STEPM(121, 1, 1, 0, 1, 1, 1, 1, 1);
  STEPM(122, 0, 2, 1, 1, 1, 1, 0, 1);  // no more advance (slab 124 is last)
  STEPM(123, 1, 0, 2, 1, 1, 1, 0, 1);
  STEPM(124, 0, 1, 0, 1, 1, 0, 0, 1);  // no x_125
  STEPM(125, 1, 2, 1, 1, 0, 0, 0, 0);  // MFMA + out[124] only, no barrier

#undef STEPM

  __syncthreads();  // full drain; outbuf visible

  // coalesced flush
  for (int i = tid; i < RPW * SEQ * 2; i += NTH) {
    int r = i / (SEQ * 2), j = i % (SEQ * 2);
    out[(row0 + r) * (SEQ * 2) + j] = outbuf[r][j];
  }
}

extern "C" void kernel_launch(void* const* d_in, const int* in_sizes, int n_in,
                              void* d_out, int out_size, void* d_ws, size_t ws_size,
                              hipStream_t stream) {
  const float* xp     = (const float*)d_in[0];
  const float* noise  = (const float*)d_in[1];
  const float* W_ih   = (const float*)d_in[2];
  const float* b_ih   = (const float*)d_in[3];
  const float* W_hh   = (const float*)d_in[4];
  const float* b_hh   = (const float*)d_in[5];
  const float* W_out  = (const float*)d_in[6];
  const float* b_out  = (const float*)d_in[7];
  float* outp         = (float*)d_out;

  rnn_fused<<<dim3(2048 / RPW), dim3(NTH), 0, stream>>>(
      xp, noise, W_ih, b_ih, W_hh, b_hh, W_out, b_out, outp);
}